// Round 10
// baseline (251.887 us; speedup 1.0000x reference)
//
#include <hip/hip_runtime.h>

typedef unsigned short u16;
typedef __bf16  bf16x8 __attribute__((ext_vector_type(8)));
typedef float   f32x4  __attribute__((ext_vector_type(4)));
typedef unsigned int u32x4 __attribute__((ext_vector_type(4)));

#define B_SZ   1024
#define V_SZ   6890
#define VPADB  6912    /* 54*128 vertex pad for blend GEMM */
#define J_SZ   52
#define NB_SZ  16
#define NPOSE  459
#define N3     20670   /* V*3 */
#define NPAD   20736   /* 162*128 = 3*VPADB: padded N for k2 GEMM (planar c-planes) */
#define KG     480     /* 459 pose + 16 betas, zero-padded to 480 */
#define KA     160     /* blend K: 52 (Ahi*Whi) + 52 (Alo*Whi) + 52 (Ahi*Wlo) + 4 pad */
#define MROWS  12288   /* B_SZ * 12: M rows of blend GEMM (b*12 + c*4 + d) */
#define MT     192     /* k4 m-tile: 16 whole batches (192 = 16*12) */

/* k_prep sub-grid: k1 blocks first (4 batches each), then k0w, then k0 tiles */
#define NK1    (B_SZ / 4)        /* 256  */
#define NK0W   (VPADB / 64)      /* 108  */
#define NK0    (648 * 15)        /* 9720 */

__constant__ int PARENTS_D[52] = {-1,0,0,0,1,2,3,4,5,6,7,8,9,9,9,12,13,14,16,17,18,19,20,22,23,
                                  20,25,26,20,28,29,20,31,32,20,34,35,21,37,38,21,40,41,21,43,44,
                                  21,46,47,21,49,50};

__device__ __forceinline__ u16 f2b(float f) {
  union { float f; unsigned u; } v; v.f = f;
  unsigned r = (v.u + 0x7FFFu + ((v.u >> 16) & 1u)) >> 16;
  return (u16)r;
}
__device__ __forceinline__ float b2f(u16 h) {
  union { unsigned u; float f; } v; v.u = ((unsigned)h) << 16;
  return v.f;
}
__device__ __forceinline__ void async16(const void* g, void* l) {
  __builtin_amdgcn_global_load_lds((const __attribute__((address_space(1))) void*)g,
                                   (__attribute__((address_space(3))) void*)l, 16, 0, 0);
}

// ---------------------------------------------------------------------------
// K_PREP: merged k1 (4 batches/block, chain 3-lane-parallel) + k0w + k0.
// (r6/r9-verified, unchanged)
// ---------------------------------------------------------------------------
__global__ __launch_bounds__(256) void k_prep(const float* __restrict__ posedirs,
                                              const float* __restrict__ shapedirs,
                                              const float* __restrict__ lbsw,
                                              const float* __restrict__ body_pose,
                                              const float* __restrict__ betas,
                                              const float* __restrict__ global_orient,
                                              const float* __restrict__ J_template,
                                              const float* __restrict__ J_shapedirs,
                                              u16* __restrict__ PDt,
                                              u16* __restrict__ WB,
                                              u16* __restrict__ AH,
                                              u16* __restrict__ PF)
{
  __shared__ __align__(16) char smem[35328];   /* max(k0 2.1K, k0w 20K, k1 4*8832) */
  const int bid = blockIdx.x;
  const int tid = threadIdx.x;

  if (bid < NK1) {
    // ================= k1 body: 4 batches per block =======================
    const int g = tid >> 6;          // group 0..3
    const int t = tid & 63;          // lane within group
    const int b = bid * 4 + g;
    char* base = smem + g * 8832;
    float (*R)[9]   = (float(*)[9])(base);            // 1872 B
    float (*jts)[3] = (float(*)[3])(base + 1872);     //  624 B
    float (*G)[12]  = (float(*)[12])(base + 2496);    // 2496 B
    u16*   AHs      = (u16*)(base + 4992);            // 3840 B

    for (int i = t; i < 12 * KA / 2; i += 64) ((unsigned*)AHs)[i] = 0u;

    if (t < J_SZ) {
      const float* d6 = (t == 0) ? &global_orient[(size_t)b * 6]
                                 : &body_pose[((size_t)b * 51 + (t - 1)) * 6];
      float a1x = d6[0], a1y = d6[1], a1z = d6[2];
      float a2x = d6[3], a2y = d6[4], a2z = d6[5];
      float inv1 = rsqrtf(a1x*a1x + a1y*a1y + a1z*a1z);
      float b1x = a1x*inv1, b1y = a1y*inv1, b1z = a1z*inv1;
      float d   = b1x*a2x + b1y*a2y + b1z*a2z;
      float ux = a2x - d*b1x, uy = a2y - d*b1y, uz = a2z - d*b1z;
      float inv2 = rsqrtf(ux*ux + uy*uy + uz*uz);
      float b2x = ux*inv2, b2y = uy*inv2, b2z = uz*inv2;
      float b3x = b1y*b2z - b1z*b2y;
      float b3y = b1z*b2x - b1x*b2z;
      float b3z = b1x*b2y - b1y*b2x;
      R[t][0]=b1x; R[t][1]=b1y; R[t][2]=b1z;
      R[t][3]=b2x; R[t][4]=b2y; R[t][5]=b2z;
      R[t][6]=b3x; R[t][7]=b3y; R[t][8]=b3z;
#pragma unroll
      for (int c = 0; c < 3; ++c) {
        float s = J_template[t*3 + c];
#pragma unroll
        for (int k = 0; k < NB_SZ; ++k)
          s += betas[(size_t)b*NB_SZ + k] * J_shapedirs[(t*3 + c)*NB_SZ + k];
        jts[t][c] = s;
      }
    }
    __syncthreads();

    if (t < 3) {   // kinematic chain: c-rows independent -> 3-lane parallel
      const int c = t;
      G[0][c*4+0] = R[0][c*3+0];
      G[0][c*4+1] = R[0][c*3+1];
      G[0][c*4+2] = R[0][c*3+2];
      G[0][c*4+3] = jts[0][c];
      for (int j = 1; j < J_SZ; ++j) {
        int p = PARENTS_D[j];
        float r0 = jts[j][0] - jts[p][0];
        float r1 = jts[j][1] - jts[p][1];
        float r2 = jts[j][2] - jts[p][2];
        float g0 = G[p][c*4+0], g1 = G[p][c*4+1], g2 = G[p][c*4+2];
        G[j][c*4+0] = g0*R[j][0] + g1*R[j][3] + g2*R[j][6];
        G[j][c*4+1] = g0*R[j][1] + g1*R[j][4] + g2*R[j][7];
        G[j][c*4+2] = g0*R[j][2] + g1*R[j][5] + g2*R[j][8];
        G[j][c*4+3] = g0*r0 + g1*r1 + g2*r2 + G[p][c*4+3];
      }
    }
    __syncthreads();

    if (t < J_SZ) {  // t_corr + AH hi/lo slices (k-slot = joint index)
      float o[12];
#pragma unroll
      for (int i = 0; i < 12; ++i) o[i] = G[t][i];
#pragma unroll
      for (int c = 0; c < 3; ++c)
        o[c*4+3] -= o[c*4+0]*jts[t][0] + o[c*4+1]*jts[t][1] + o[c*4+2]*jts[t][2];
#pragma unroll
      for (int cd = 0; cd < 12; ++cd) {
        u16 hi = f2b(o[cd]);
        u16 lo = f2b(o[cd] - b2f(hi));
        AHs[cd*KA + t]        = hi;   // * Whi
        AHs[cd*KA + 52 + t]   = lo;   // * Whi
        AHs[cd*KA + 104 + t]  = hi;   // * Wlo
      }
    }

    for (int k = t; k < KG; k += 64) {  // PF row: pose_feature | betas | 0-pad
      float val = 0.f;
      if (k < NPOSE) {
        int j  = k / 9 + 1;
        int rc = k - (j - 1) * 9;
        val = R[j][rc] - ((rc == 0 || rc == 4 || rc == 8) ? 1.f : 0.f);
      } else if (k < NPOSE + NB_SZ) {
        val = betas[(size_t)b*NB_SZ + (k - NPOSE)];
      }
      PF[(size_t)b*KG + k] = f2b(val);
    }

    __syncthreads();
    unsigned* dst = (unsigned*)(AH + (size_t)b * 12 * KA);
    for (int i = t; i < 12 * KA / 2; i += 64) dst[i] = ((const unsigned*)AHs)[i];

  } else if (bid < NK1 + NK0W) {
    // ================= k0w body: WB[v][160] ===============================
    u16* wtile = (u16*)smem;                  // 64 * KA u16 = 20480 B
    const int v0  = (bid - NK1) * 64;
    const int vl  = tid >> 2;
    const int v   = v0 + vl;
    const int jseg = (tid & 3) * 13;

    wtile[vl * KA + 156 + (tid & 3)] = 0;     // zero k 156..159 pad

#pragma unroll
    for (int jj = 0; jj < 13; ++jj) {
      int j = jseg + jj;
      float wv = (v < V_SZ) ? lbsw[(size_t)v * J_SZ + j] : 0.f;
      u16 hi = f2b(wv);
      u16 lo = f2b(wv - b2f(hi));
      wtile[vl * KA + j]        = hi;   // pairs with A_hi
      wtile[vl * KA + 52 + j]   = hi;   // pairs with A_lo
      wtile[vl * KA + 104 + j]  = lo;   // pairs with A_hi
    }
    __syncthreads();
    u32x4*       dst = (u32x4*)(WB + (size_t)v0 * KA);
    const u32x4* src = (const u32x4*)wtile;
    for (int i = tid; i < 64 * KA / 8; i += 256) dst[i] = src[i];

  } else {
    // ================= k0 body: PDt[n'][k], planar n' =====================
    u16 (*tile)[33] = (u16(*)[33])smem;       // 32*33*2 = 2112 B
    const int cb = bid - NK1 - NK0W;
    const int tx = tid & 31;
    const int ty = tid >> 5;
    const int n0 = (cb % 648) * 32;
    const int k0 = (cb / 648) * 32;
#pragma unroll
    for (int i = 0; i < 4; ++i) {
      int k = k0 + ty + i*8;
      int n = n0 + tx;
      float val = 0.f;
      if (n < N3) {
        if (k < NPOSE)              val = posedirs[(size_t)k * N3 + n];
        else if (k < NPOSE + NB_SZ) val = shapedirs[(size_t)n * NB_SZ + (k - NPOSE)];
      }
      tile[ty + i*8][tx] = f2b(val);
    }
    __syncthreads();
#pragma unroll
    for (int i = 0; i < 4; ++i) {
      int n = n0 + ty + i*8;
      int k = k0 + tx;
      int vv = n / 3;                 // planar permute: n' = (n%3)*VPADB + n/3
      int cc = n - vv * 3;            // bijective on [0, NPAD); pad rows zeroed
      PDt[((size_t)cc * VPADB + vv) * KG + k] = tile[tx][ty + i*8];
    }
  }
}

// ---------------------------------------------------------------------------
// K2: v_posed = PF(B,KG) @ PDt^T + bias. (r9-verified, unchanged: XCD-grouped
// 1D grid 1344, 2-buffer counted-vmcnt K-loop, planar VP output.)
// ---------------------------------------------------------------------------
__global__ __launch_bounds__(256) void k2_gemm(const u16* __restrict__ PF,
                                               const u16* __restrict__ PDt,
                                               const float* __restrict__ vtmpl,
                                               u16* __restrict__ VP)
{
  __shared__ __align__(16) u16 lA[2][4096];
  __shared__ __align__(16) u16 lB[2][4096];
  const int bid = blockIdx.x;
  const int nt  = (bid & 7) + ((bid >> 6) << 3);   // n-tile 0..167 (use <162)
  const int bt  = (bid >> 3) & 7;                  // b-tile 0..7
  if (nt >= 162) return;
  const int tid  = threadIdx.x;
  const int lane = tid & 63;
  const int w    = tid >> 6;
  const int n0   = nt * 128;
  const int b0   = bt * 128;
  const int moff = (w & 1) * 64;
  const int noff = (w >> 1) * 64;
  const int q    = lane >> 4;
  const int lrow = lane & 15;

  f32x4 acc[4][4];
#pragma unroll
  for (int i = 0; i < 4; ++i)
#pragma unroll
    for (int j = 0; j < 4; ++j) { f32x4 z = {0.f,0.f,0.f,0.f}; acc[i][j] = z; }

  int aoff[4], boff[4];
#pragma unroll
  for (int i = 0; i < 4; ++i) {
    int ra = moff + i*16 + lrow;
    aoff[i] = ra*32 + (q ^ ((ra + (ra >> 2)) & 3)) * 8;
    int rb = noff + i*16 + lrow;
    boff[i] = rb*32 + (q ^ ((rb + (rb >> 2)) & 3)) * 8;
  }
  int srow[2], schunk[2];
#pragma unroll
  for (int t = 0; t < 2; ++t) {
    int i = (t*4 + w)*64 + lane;     // slot in [0,512)
    int r = i >> 2;
    srow[t]   = r;
    schunk[t] = (i & 3) ^ ((r + (r >> 2)) & 3);
  }

#define K2_STAGE(buf, seg)                                                          \
  {                                                                                 \
    const int kk = (seg) * 32;                                                      \
    _Pragma("unroll")                                                               \
    for (int t = 0; t < 2; ++t) {                                                   \
      async16(PF  + (size_t)(b0 + srow[t])*KG + kk + schunk[t]*8,                   \
              &lA[buf][(t*4 + w)*512]);                                             \
      async16(PDt + (size_t)(n0 + srow[t])*KG + kk + schunk[t]*8,                   \
              &lB[buf][(t*4 + w)*512]);                                             \
    }                                                                               \
  }

  K2_STAGE(0, 0);

  for (int seg = 0; seg < 15; ++seg) {
    const int cur = seg & 1;
    if (seg < 14) K2_STAGE(cur ^ 1, seg + 1);
    __builtin_amdgcn_sched_barrier(0);
    if (seg < 14) asm volatile("s_waitcnt vmcnt(4)" ::: "memory");
    else          asm volatile("s_waitcnt vmcnt(0)" ::: "memory");
    __builtin_amdgcn_s_barrier();
    __builtin_amdgcn_sched_barrier(0);
    bf16x8 af[4], bfv[4];
#pragma unroll
    for (int i = 0; i < 4; ++i) af[i]  = *(const bf16x8*)&lA[cur][aoff[i]];
#pragma unroll
    for (int i = 0; i < 4; ++i) bfv[i] = *(const bf16x8*)&lB[cur][boff[i]];
#pragma unroll
    for (int i = 0; i < 4; ++i)
#pragma unroll
      for (int j = 0; j < 4; ++j)
        acc[i][j] = __builtin_amdgcn_mfma_f32_16x16x32_bf16(af[i], bfv[j], acc[i][j], 0, 0, 0);
    if (seg < 14) {                     // protect buf reuse by next stage
      __builtin_amdgcn_sched_barrier(0);
      __builtin_amdgcn_s_barrier();
    }
  }
#undef K2_STAGE

#pragma unroll
  for (int i = 0; i < 4; ++i) {
    int brow = b0 + moff + i*16 + q*4;
#pragma unroll
    for (int j = 0; j < 4; ++j) {
      int np = n0 + noff + j*16 + lrow;        // planar column: c*VPADB + v
      int vv = np % VPADB;
      int cc = np / VPADB;
      float bias = (vv < V_SZ) ? vtmpl[vv*3 + cc] : 0.f;
#pragma unroll
      for (int r = 0; r < 4; ++r)
        VP[(size_t)(brow + r)*NPAD + np] = f2b(acc[i][j][r] + bias);
    }
  }
}

// ---------------------------------------------------------------------------
// K4: MFMA blend, M = B*12, m-tile 192 (= exactly 16 batches, no boundary
// sharing; blocks 5184 -> 3456). r6-verified 2-buffer counted-vmcnt loop,
// wait count 5 (= loads/seg: 3 A + 2 B). VP epilogue operands staged via
// coalesced global_load_lds into VPL (48 rows x 256 B = 12 KB), issued
// FIRST so they drain under the first counted wait (T14). LDS 52 KB.
// ---------------------------------------------------------------------------
__global__ __launch_bounds__(256) void k4_blend(const u16* __restrict__ AH,
                                                const u16* __restrict__ WB,
                                                const u16* __restrict__ VP,
                                                const float* __restrict__ transl,
                                                float* __restrict__ out)
{
  __shared__ __align__(16) u16 lA[2][MT*32];     // 2 x 12 KB, swizzled [row][32k]
  __shared__ __align__(16) u16 lB[2][128*32];    // 2 x 8 KB
  __shared__ __align__(16) u16 VPL[48*128];      // 12 KB: [(bl*3+c)][v0..v127]
  const int tid  = threadIdx.x;
  const int lane = tid & 63;
  const int w    = tid >> 6;
  const int n0   = blockIdx.x * 128;             // vertex tile
  const int m0   = blockIdx.y * MT;              // row tile = batches [16*by,+16)
  const int bfirst = blockIdx.y * 16;
  const int mhalf = (w >> 1) * 96;
  const int noff  = (w & 1) * 64;
  const int q    = lane >> 4;
  const int lrow = lane & 15;

  int srowA[3], schunkA[3];
#pragma unroll
  for (int t = 0; t < 3; ++t) {
    int i = (t*4 + w)*64 + lane;                 // slot in [0,768)
    int r = i >> 2;
    srowA[t]   = r;
    schunkA[t] = (i & 3) ^ ((r + (r >> 2)) & 3);
  }
  int srowB[2], schunkB[2];
#pragma unroll
  for (int t = 0; t < 2; ++t) {
    int i = (t*4 + w)*64 + lane;                 // slot in [0,512)
    int r = i >> 2;
    srowB[t]   = r;
    schunkB[t] = (i & 3) ^ ((r + (r >> 2)) & 3);
  }

#define K4_STAGE(buf, seg)                                                          \
  {                                                                                 \
    const int kk = (seg) * 32;                                                      \
    _Pragma("unroll")                                                               \
    for (int t = 0; t < 3; ++t)                                                     \
      async16(AH + (size_t)(m0 + srowA[t])*KA + kk + schunkA[t]*8,                  \
              &lA[buf][(t*4 + w)*512]);                                             \
    _Pragma("unroll")                                                               \
    for (int t = 0; t < 2; ++t)                                                     \
      async16(WB + (size_t)(n0 + srowB[t])*KA + kk + schunkB[t]*8,                  \
              &lB[buf][(t*4 + w)*512]);                                             \
  }

  // ---- VPL stage FIRST (oldest vmem -> drains under first counted wait).
  // 48 rows (bl*3+c) x 256 B, linear; slot s=(t*4+w)*64+lane -> byte s*16.
#pragma unroll
  for (int t = 0; t < 3; ++t) {
    int s   = (t*4 + w)*64 + lane;               // 0..767
    int row = s >> 4;                            // bl*3 + c
    int col = s & 15;                            // 16B unit within row
    int bl  = row / 3;
    int c   = row - bl*3;
    async16(VP + (size_t)(bfirst + bl)*NPAD + (size_t)c*VPADB + n0 + col*8,
            &VPL[(t*4 + w)*512]);
  }

  // ---- prologue stage seg0
  K4_STAGE(0, 0);

  f32x4 acc[6][4];
#pragma unroll
  for (int i = 0; i < 6; ++i)
#pragma unroll
    for (int j = 0; j < 4; ++j) { f32x4 z = {0.f,0.f,0.f,0.f}; acc[i][j] = z; }

  int aoff[6], boff[4];
#pragma unroll
  for (int i = 0; i < 6; ++i) {
    int ra = mhalf + i*16 + lrow;
    aoff[i] = ra*32 + (q ^ ((ra + (ra >> 2)) & 3)) * 8;
  }
#pragma unroll
  for (int j = 0; j < 4; ++j) {
    int rb = noff + j*16 + lrow;
    boff[j] = rb*32 + (q ^ ((rb + (rb >> 2)) & 3)) * 8;
  }

  // ---- 2-buffer counted-vmcnt K-loop (5 loads/seg in flight)
#pragma unroll
  for (int seg = 0; seg < 5; ++seg) {
    const int cur = seg & 1;
    if (seg < 4) K4_STAGE(cur ^ 1, seg + 1);
    __builtin_amdgcn_sched_barrier(0);
    if (seg < 4) asm volatile("s_waitcnt vmcnt(5)" ::: "memory");
    else         asm volatile("s_waitcnt vmcnt(0)" ::: "memory");
    __builtin_amdgcn_s_barrier();
    __builtin_amdgcn_sched_barrier(0);
    bf16x8 af[6], bfv[4];
#pragma unroll
    for (int i = 0; i < 6; ++i) af[i]  = *(const bf16x8*)&lA[cur][aoff[i]];
#pragma unroll
    for (int j = 0; j < 4; ++j) bfv[j] = *(const bf16x8*)&lB[cur][boff[j]];
#pragma unroll
    for (int i = 0; i < 6; ++i)
#pragma unroll
      for (int j = 0; j < 4; ++j)
        acc[i][j] = __builtin_amdgcn_mfma_f32_16x16x32_bf16(af[i], bfv[j], acc[i][j], 0, 0, 0);
    if (seg < 4) {                      // protect buf reuse by next stage
      __builtin_amdgcn_sched_barrier(0);
      __builtin_amdgcn_s_barrier();
    }
  }
#undef K4_STAGE

  // ---- fused epilogue: every lane holds one full T-row (b', c'); P from VPL
#pragma unroll
  for (int i = 0; i < 6; ++i) {
    int gq = (m0 + mhalf + i*16) / 4 + q;        // quarter-row index
    int bp = gq / 3;                             // batch
    int cp = gq - bp*3;                          // coordinate row
    int bl = bp - bfirst;                        // 0..15
    float tr = transl[bp*3 + cp];
    float* ob = out + (size_t)bp * (V_SZ * 3);
#pragma unroll
    for (int j = 0; j < 4; ++j) {
      const int vv = noff + j*16 + lrow;         // 0..127
      const int v  = n0 + vv;
      if (v < V_SZ) {
        float p0 = b2f(VPL[(bl*3 + 0)*128 + vv]);
        float p1 = b2f(VPL[(bl*3 + 1)*128 + vv]);
        float p2 = b2f(VPL[(bl*3 + 2)*128 + vv]);
        f32x4 a = acc[i][j];
        ob[(size_t)v*3 + cp] = a[0]*p0 + a[1]*p1 + a[2]*p2 + a[3] + tr;
      }
    }
  }
}

// ---------------------------------------------------------------------------
extern "C" void kernel_launch(void* const* d_in, const int* in_sizes, int n_in,
                              void* d_out, int out_size, void* d_ws, size_t ws_size,
                              hipStream_t stream) {
  const float* body_pose     = (const float*)d_in[0];
  const float* betas         = (const float*)d_in[1];
  const float* global_orient = (const float*)d_in[2];
  const float* transl        = (const float*)d_in[3];
  const float* v_template    = (const float*)d_in[4];
  const float* shapedirs     = (const float*)d_in[5];
  const float* posedirs      = (const float*)d_in[6];
  const float* J_template    = (const float*)d_in[7];
  const float* J_shapedirs   = (const float*)d_in[8];
  const float* lbsw          = (const float*)d_in[9];
  float* out = (float*)d_out;

  // workspace layout (67.6 MB total, all 16B-aligned):
  //   [0,        983040)   PF   1024*480*2
  //   [1048576,  4980736)  AH   12288*160*2 = 3.93 MB  (prep->k4)
  //   [6291456,  8503296)  WB   6912*160*2  = 2.21 MB  (prep->k4)
  //   [8503296, 28409856)  PDt  20736*480*2 = 19.9 MB  (prep->k2, planar rows)
  //   [28409856,70877184)  VP   1024*20736*2= 42.5 MB  (k2->k4, planar [b][c][v])
  char* ws = (char*)d_ws;
  u16* PF  = (u16*)(ws);
  u16* AH  = (u16*)(ws + 1048576u);
  u16* WB  = (u16*)(ws + 6291456u);
  u16* PDt = (u16*)(ws + 8503296u);
  u16* VP  = (u16*)(ws + 28409856u);

  k_prep<<<dim3(NK1 + NK0W + NK0), dim3(256), 0, stream>>>(
      posedirs, shapedirs, lbsw, body_pose, betas, global_orient,
      J_template, J_shapedirs, PDt, WB, AH, PF);
  k2_gemm<<<dim3(1344), dim3(256), 0, stream>>>(PF, PDt, v_template, VP);
  k4_blend<<<dim3(VPADB / 128, MROWS / MT), dim3(256), 0, stream>>>(AH, WB, VP, transl, out);
}

// Round 11
// 245.930 us; speedup vs baseline: 1.0242x; 1.0242x over previous
//
#include <hip/hip_runtime.h>

typedef unsigned short u16;
typedef __bf16  bf16x8 __attribute__((ext_vector_type(8)));
typedef float   f32x4  __attribute__((ext_vector_type(4)));
typedef unsigned int u32x4 __attribute__((ext_vector_type(4)));

#define B_SZ   1024
#define V_SZ   6890
#define VPADB  6912    /* 54*128 vertex pad for blend GEMM */
#define J_SZ   52
#define NB_SZ  16
#define NPOSE  459
#define N3     20670   /* V*3 */
#define NPAD   20736   /* 162*128 = 3*VPADB: padded N for k2 GEMM (planar c-planes) */
#define KG     480     /* 459 pose + 16 betas, zero-padded to 480 */
#define KA     160     /* blend K: 52 (Ahi*Whi) + 52 (Alo*Whi) + 52 (Ahi*Wlo) + 4 pad */
#define MROWS  12288   /* B_SZ * 12: M rows of blend GEMM (b*12 + c*4 + d) */

/* k_prep sub-grid: k1 blocks first (4 batches each), then k0w, then k0 tiles */
#define NK1    (B_SZ / 4)        /* 256  */
#define NK0W   (VPADB / 64)      /* 108  */
#define NK0    (648 * 8)         /* 5184: 32n x 64k tiles */

__constant__ int PARENTS_D[52] = {-1,0,0,0,1,2,3,4,5,6,7,8,9,9,9,12,13,14,16,17,18,19,20,22,23,
                                  20,25,26,20,28,29,20,31,32,20,34,35,21,37,38,21,40,41,21,43,44,
                                  21,46,47,21,49,50};

__device__ __forceinline__ u16 f2b(float f) {
  union { float f; unsigned u; } v; v.f = f;
  unsigned r = (v.u + 0x7FFFu + ((v.u >> 16) & 1u)) >> 16;
  return (u16)r;
}
__device__ __forceinline__ float b2f(u16 h) {
  union { unsigned u; float f; } v; v.u = ((unsigned)h) << 16;
  return v.f;
}
__device__ __forceinline__ void async16(const void* g, void* l) {
  __builtin_amdgcn_global_load_lds((const __attribute__((address_space(1))) void*)g,
                                   (__attribute__((address_space(3))) void*)l, 16, 0, 0);
}

// ---------------------------------------------------------------------------
// K_PREP: merged k1 (4 batches/block, chain 3-lane-parallel) + k0w + k0.
// k0 retiled to 32n x 64k: 16B u32x4 stores, each 128-B PDt line written
// whole by ONE block (was: 64-B half-lines from 2 different blocks/XCDs ->
// partial-line write amplification). Loads stay 128-B coalesced per k-row.
// ---------------------------------------------------------------------------
__global__ __launch_bounds__(256) void k_prep(const float* __restrict__ posedirs,
                                              const float* __restrict__ shapedirs,
                                              const float* __restrict__ lbsw,
                                              const float* __restrict__ body_pose,
                                              const float* __restrict__ betas,
                                              const float* __restrict__ global_orient,
                                              const float* __restrict__ J_template,
                                              const float* __restrict__ J_shapedirs,
                                              u16* __restrict__ PDt,
                                              u16* __restrict__ WB,
                                              u16* __restrict__ AH,
                                              u16* __restrict__ PF)
{
  __shared__ __align__(16) char smem[35328];   /* max(k0 4.6K, k0w 20K, k1 4*8832) */
  const int bid = blockIdx.x;
  const int tid = threadIdx.x;

  if (bid < NK1) {
    // ================= k1 body: 4 batches per block =======================
    const int g = tid >> 6;          // group 0..3
    const int t = tid & 63;          // lane within group
    const int b = bid * 4 + g;
    char* base = smem + g * 8832;
    float (*R)[9]   = (float(*)[9])(base);            // 1872 B
    float (*jts)[3] = (float(*)[3])(base + 1872);     //  624 B
    float (*G)[12]  = (float(*)[12])(base + 2496);    // 2496 B
    u16*   AHs      = (u16*)(base + 4992);            // 3840 B

    for (int i = t; i < 12 * KA / 2; i += 64) ((unsigned*)AHs)[i] = 0u;

    if (t < J_SZ) {
      const float* d6 = (t == 0) ? &global_orient[(size_t)b * 6]
                                 : &body_pose[((size_t)b * 51 + (t - 1)) * 6];
      float a1x = d6[0], a1y = d6[1], a1z = d6[2];
      float a2x = d6[3], a2y = d6[4], a2z = d6[5];
      float inv1 = rsqrtf(a1x*a1x + a1y*a1y + a1z*a1z);
      float b1x = a1x*inv1, b1y = a1y*inv1, b1z = a1z*inv1;
      float d   = b1x*a2x + b1y*a2y + b1z*a2z;
      float ux = a2x - d*b1x, uy = a2y - d*b1y, uz = a2z - d*b1z;
      float inv2 = rsqrtf(ux*ux + uy*uy + uz*uz);
      float b2x = ux*inv2, b2y = uy*inv2, b2z = uz*inv2;
      float b3x = b1y*b2z - b1z*b2y;
      float b3y = b1z*b2x - b1x*b2z;
      float b3z = b1x*b2y - b1y*b2x;
      R[t][0]=b1x; R[t][1]=b1y; R[t][2]=b1z;
      R[t][3]=b2x; R[t][4]=b2y; R[t][5]=b2z;
      R[t][6]=b3x; R[t][7]=b3y; R[t][8]=b3z;
#pragma unroll
      for (int c = 0; c < 3; ++c) {
        float s = J_template[t*3 + c];
#pragma unroll
        for (int k = 0; k < NB_SZ; ++k)
          s += betas[(size_t)b*NB_SZ + k] * J_shapedirs[(t*3 + c)*NB_SZ + k];
        jts[t][c] = s;
      }
    }
    __syncthreads();

    if (t < 3) {   // kinematic chain: c-rows independent -> 3-lane parallel
      const int c = t;
      G[0][c*4+0] = R[0][c*3+0];
      G[0][c*4+1] = R[0][c*3+1];
      G[0][c*4+2] = R[0][c*3+2];
      G[0][c*4+3] = jts[0][c];
      for (int j = 1; j < J_SZ; ++j) {
        int p = PARENTS_D[j];
        float r0 = jts[j][0] - jts[p][0];
        float r1 = jts[j][1] - jts[p][1];
        float r2 = jts[j][2] - jts[p][2];
        float g0 = G[p][c*4+0], g1 = G[p][c*4+1], g2 = G[p][c*4+2];
        G[j][c*4+0] = g0*R[j][0] + g1*R[j][3] + g2*R[j][6];
        G[j][c*4+1] = g0*R[j][1] + g1*R[j][4] + g2*R[j][7];
        G[j][c*4+2] = g0*R[j][2] + g1*R[j][5] + g2*R[j][8];
        G[j][c*4+3] = g0*r0 + g1*r1 + g2*r2 + G[p][c*4+3];
      }
    }
    __syncthreads();

    if (t < J_SZ) {  // t_corr + AH hi/lo slices (k-slot = joint index)
      float o[12];
#pragma unroll
      for (int i = 0; i < 12; ++i) o[i] = G[t][i];
#pragma unroll
      for (int c = 0; c < 3; ++c)
        o[c*4+3] -= o[c*4+0]*jts[t][0] + o[c*4+1]*jts[t][1] + o[c*4+2]*jts[t][2];
#pragma unroll
      for (int cd = 0; cd < 12; ++cd) {
        u16 hi = f2b(o[cd]);
        u16 lo = f2b(o[cd] - b2f(hi));
        AHs[cd*KA + t]        = hi;   // * Whi
        AHs[cd*KA + 52 + t]   = lo;   // * Whi
        AHs[cd*KA + 104 + t]  = hi;   // * Wlo
      }
    }

    for (int k = t; k < KG; k += 64) {  // PF row: pose_feature | betas | 0-pad
      float val = 0.f;
      if (k < NPOSE) {
        int j  = k / 9 + 1;
        int rc = k - (j - 1) * 9;
        val = R[j][rc] - ((rc == 0 || rc == 4 || rc == 8) ? 1.f : 0.f);
      } else if (k < NPOSE + NB_SZ) {
        val = betas[(size_t)b*NB_SZ + (k - NPOSE)];
      }
      PF[(size_t)b*KG + k] = f2b(val);
    }

    __syncthreads();
    unsigned* dst = (unsigned*)(AH + (size_t)b * 12 * KA);
    for (int i = t; i < 12 * KA / 2; i += 64) dst[i] = ((const unsigned*)AHs)[i];

  } else if (bid < NK1 + NK0W) {
    // ================= k0w body: WB[v][160] ===============================
    u16* wtile = (u16*)smem;                  // 64 * KA u16 = 20480 B
    const int v0  = (bid - NK1) * 64;
    const int vl  = tid >> 2;
    const int v   = v0 + vl;
    const int jseg = (tid & 3) * 13;

    wtile[vl * KA + 156 + (tid & 3)] = 0;     // zero k 156..159 pad

#pragma unroll
    for (int jj = 0; jj < 13; ++jj) {
      int j = jseg + jj;
      float wv = (v < V_SZ) ? lbsw[(size_t)v * J_SZ + j] : 0.f;
      u16 hi = f2b(wv);
      u16 lo = f2b(wv - b2f(hi));
      wtile[vl * KA + j]        = hi;   // pairs with A_hi
      wtile[vl * KA + 52 + j]   = hi;   // pairs with A_lo
      wtile[vl * KA + 104 + j]  = lo;   // pairs with A_hi
    }
    __syncthreads();
    u32x4*       dst = (u32x4*)(WB + (size_t)v0 * KA);
    const u32x4* src = (const u32x4*)wtile;
    for (int i = tid; i < 64 * KA / 8; i += 256) dst[i] = src[i];

  } else {
    // ================= k0 body: PDt[n'][k], planar n', 32n x 64k tile =====
    u16* tile = (u16*)smem;                   // [32][72] u16, 4608 B
    const int cb = bid - NK1 - NK0W;
    const int nt = cb % 648;
    const int kt = cb / 648;                  // 0..7
    const int n0 = nt * 32;
    const int k0 = kt * 64;
    const int tx = tid & 31;                  // n lane
    const int ty = tid >> 5;                  // 0..7
    const int n  = n0 + tx;
#pragma unroll
    for (int i = 0; i < 8; ++i) {
      int k = k0 + ty + i*8;                  // k0..k0+63
      float val = 0.f;
      if (n < N3) {
        if (k < NPOSE)              val = posedirs[(size_t)k * N3 + n];
        else if (k < NPOSE + NB_SZ) val = shapedirs[(size_t)n * NB_SZ + (k - NPOSE)];
      }
      tile[tx*72 + ty + i*8] = f2b(val);
    }
    __syncthreads();
    // store: 8 threads cover one n-row's 64 k's = 128 B contiguous (full line)
    const int nl = tid >> 3;                  // 0..31
    const int ks = (tid & 7) * 8;             // 0,8,..,56
    const int kb = k0 + ks;
    if (kb < KG) {
      int n2 = n0 + nl;                       // < 20736 by grid
      int vv = n2 / 3;
      int cc = n2 - vv * 3;                   // planar permute (bijective)
      *(u32x4*)&PDt[((size_t)cc * VPADB + vv) * KG + kb] =
          *(const u32x4*)&tile[nl*72 + ks];
    }
  }
}

// ---------------------------------------------------------------------------
// K2: v_posed = PF(B,KG) @ PDt^T + bias. (r9-verified, unchanged: XCD-grouped
// 1D grid 1344, 2-buffer counted-vmcnt K-loop, planar VP output.)
// ---------------------------------------------------------------------------
__global__ __launch_bounds__(256) void k2_gemm(const u16* __restrict__ PF,
                                               const u16* __restrict__ PDt,
                                               const float* __restrict__ vtmpl,
                                               u16* __restrict__ VP)
{
  __shared__ __align__(16) u16 lA[2][4096];
  __shared__ __align__(16) u16 lB[2][4096];
  const int bid = blockIdx.x;
  const int nt  = (bid & 7) + ((bid >> 6) << 3);   // n-tile 0..167 (use <162)
  const int bt  = (bid >> 3) & 7;                  // b-tile 0..7
  if (nt >= 162) return;
  const int tid  = threadIdx.x;
  const int lane = tid & 63;
  const int w    = tid >> 6;
  const int n0   = nt * 128;
  const int b0   = bt * 128;
  const int moff = (w & 1) * 64;
  const int noff = (w >> 1) * 64;
  const int q    = lane >> 4;
  const int lrow = lane & 15;

  f32x4 acc[4][4];
#pragma unroll
  for (int i = 0; i < 4; ++i)
#pragma unroll
    for (int j = 0; j < 4; ++j) { f32x4 z = {0.f,0.f,0.f,0.f}; acc[i][j] = z; }

  int aoff[4], boff[4];
#pragma unroll
  for (int i = 0; i < 4; ++i) {
    int ra = moff + i*16 + lrow;
    aoff[i] = ra*32 + (q ^ ((ra + (ra >> 2)) & 3)) * 8;
    int rb = noff + i*16 + lrow;
    boff[i] = rb*32 + (q ^ ((rb + (rb >> 2)) & 3)) * 8;
  }
  int srow[2], schunk[2];
#pragma unroll
  for (int t = 0; t < 2; ++t) {
    int i = (t*4 + w)*64 + lane;     // slot in [0,512)
    int r = i >> 2;
    srow[t]   = r;
    schunk[t] = (i & 3) ^ ((r + (r >> 2)) & 3);
  }

#define K2_STAGE(buf, seg)                                                          \
  {                                                                                 \
    const int kk = (seg) * 32;                                                      \
    _Pragma("unroll")                                                               \
    for (int t = 0; t < 2; ++t) {                                                   \
      async16(PF  + (size_t)(b0 + srow[t])*KG + kk + schunk[t]*8,                   \
              &lA[buf][(t*4 + w)*512]);                                             \
      async16(PDt + (size_t)(n0 + srow[t])*KG + kk + schunk[t]*8,                   \
              &lB[buf][(t*4 + w)*512]);                                             \
    }                                                                               \
  }

  K2_STAGE(0, 0);

  for (int seg = 0; seg < 15; ++seg) {
    const int cur = seg & 1;
    if (seg < 14) K2_STAGE(cur ^ 1, seg + 1);
    __builtin_amdgcn_sched_barrier(0);
    if (seg < 14) asm volatile("s_waitcnt vmcnt(4)" ::: "memory");
    else          asm volatile("s_waitcnt vmcnt(0)" ::: "memory");
    __builtin_amdgcn_s_barrier();
    __builtin_amdgcn_sched_barrier(0);
    bf16x8 af[4], bfv[4];
#pragma unroll
    for (int i = 0; i < 4; ++i) af[i]  = *(const bf16x8*)&lA[cur][aoff[i]];
#pragma unroll
    for (int i = 0; i < 4; ++i) bfv[i] = *(const bf16x8*)&lB[cur][boff[i]];
#pragma unroll
    for (int i = 0; i < 4; ++i)
#pragma unroll
      for (int j = 0; j < 4; ++j)
        acc[i][j] = __builtin_amdgcn_mfma_f32_16x16x32_bf16(af[i], bfv[j], acc[i][j], 0, 0, 0);
    if (seg < 14) {                     // protect buf reuse by next stage
      __builtin_amdgcn_sched_barrier(0);
      __builtin_amdgcn_s_barrier();
    }
  }
#undef K2_STAGE

#pragma unroll
  for (int i = 0; i < 4; ++i) {
    int brow = b0 + moff + i*16 + q*4;
#pragma unroll
    for (int j = 0; j < 4; ++j) {
      int np = n0 + noff + j*16 + lrow;        // planar column: c*VPADB + v
      int vv = np % VPADB;
      int cc = np / VPADB;
      float bias = (vv < V_SZ) ? vtmpl[vv*3 + cc] : 0.f;
#pragma unroll
      for (int r = 0; r < 4; ++r)
        VP[(size_t)(brow + r)*NPAD + np] = f2b(acc[i][j][r] + bias);
    }
  }
}

// ---------------------------------------------------------------------------
// K4: MFMA blend, M = B*12. EXACT r9 structure (best measured: 70.5 µs):
// 2-buffer counted-vmcnt K-loop, planar VP prefetch first, fused epilogue.
// ---------------------------------------------------------------------------
__global__ __launch_bounds__(256) void k4_blend(const u16* __restrict__ AH,
                                                const u16* __restrict__ WB,
                                                const u16* __restrict__ VP,
                                                const float* __restrict__ transl,
                                                float* __restrict__ out)
{
  __shared__ __align__(16) u16 lA[2][4096];   // 2 x 8 KB, swizzled [row][32k]
  __shared__ __align__(16) u16 lB[2][4096];   // 2 x 8 KB
  const int tid  = threadIdx.x;
  const int lane = tid & 63;
  const int w    = tid >> 6;
  const int n0   = blockIdx.x * 128;          // vertex tile
  const int m0   = blockIdx.y * 128;          // (b,cd12) row tile
  const int moff = (w & 1) * 64;
  const int noff = (w >> 1) * 64;
  const int q    = lane >> 4;
  const int lrow = lane & 15;

  int srow[2], schunk[2];
#pragma unroll
  for (int t = 0; t < 2; ++t) {
    int i = (t*4 + w)*64 + lane;
    int r = i >> 2;
    srow[t]   = r;
    schunk[t] = (i & 3) ^ ((r + (r >> 2)) & 3);
  }

#define K4_STAGE(buf, seg)                                                          \
  {                                                                                 \
    const int kk = (seg) * 32;                                                      \
    _Pragma("unroll")                                                               \
    for (int t = 0; t < 2; ++t) {                                                   \
      async16(AH + (size_t)(m0 + srow[t])*KA + kk + schunk[t]*8,                    \
              &lA[buf][(t*4 + w)*512]);                                             \
      async16(WB + (size_t)(n0 + srow[t])*KA + kk + schunk[t]*8,                    \
              &lB[buf][(t*4 + w)*512]);                                             \
    }                                                                               \
  }

  // ---- epilogue operand prefetch FIRST (oldest vmem -> drains under stage).
  int   bp[4], cp[4];
#pragma unroll
  for (int i = 0; i < 4; ++i) {
    int gq = (m0 + moff + i*16) / 4 + q;   // quarter-row index
    bp[i] = gq / 3;                        // batch
    cp[i] = gq - bp[i]*3;                  // coordinate row
  }
  u16 pv[4][4][3];
#pragma unroll
  for (int i = 0; i < 4; ++i) {
    const u16* vpb = VP + (size_t)bp[i] * NPAD;
#pragma unroll
    for (int j = 0; j < 4; ++j) {
      const int v = n0 + noff + j*16 + lrow;   // < VPADB; planes contiguous in v
      pv[i][j][0] = vpb[0*VPADB + v];
      pv[i][j][1] = vpb[1*VPADB + v];
      pv[i][j][2] = vpb[2*VPADB + v];
    }
  }
  float tr[4];
#pragma unroll
  for (int i = 0; i < 4; ++i) tr[i] = transl[bp[i]*3 + cp[i]];

  // ---- prologue stage seg0
  K4_STAGE(0, 0);

  f32x4 acc[4][4];
#pragma unroll
  for (int i = 0; i < 4; ++i)
#pragma unroll
    for (int j = 0; j < 4; ++j) { f32x4 z = {0.f,0.f,0.f,0.f}; acc[i][j] = z; }

  int aoff[4], boff[4];
#pragma unroll
  for (int i = 0; i < 4; ++i) {
    int ra = moff + i*16 + lrow;
    aoff[i] = ra*32 + (q ^ ((ra + (ra >> 2)) & 3)) * 8;
    int rb = noff + i*16 + lrow;
    boff[i] = rb*32 + (q ^ ((rb + (rb >> 2)) & 3)) * 8;
  }

  // ---- T4 2-phase K-loop: stage(seg+1) stays in flight across the barrier
#pragma unroll
  for (int seg = 0; seg < 5; ++seg) {
    const int cur = seg & 1;
    if (seg < 4) K4_STAGE(cur ^ 1, seg + 1);
    __builtin_amdgcn_sched_barrier(0);
    if (seg < 4) asm volatile("s_waitcnt vmcnt(4)" ::: "memory");
    else         asm volatile("s_waitcnt vmcnt(0)" ::: "memory");
    __builtin_amdgcn_s_barrier();
    __builtin_amdgcn_sched_barrier(0);
    bf16x8 af[4], bfv[4];
#pragma unroll
    for (int i = 0; i < 4; ++i) af[i]  = *(const bf16x8*)&lA[cur][aoff[i]];
#pragma unroll
    for (int i = 0; i < 4; ++i) bfv[i] = *(const bf16x8*)&lB[cur][boff[i]];
#pragma unroll
    for (int i = 0; i < 4; ++i)
#pragma unroll
      for (int j = 0; j < 4; ++j)
        acc[i][j] = __builtin_amdgcn_mfma_f32_16x16x32_bf16(af[i], bfv[j], acc[i][j], 0, 0, 0);
    if (seg < 4) {                      // protect buf reuse by next stage
      __builtin_amdgcn_sched_barrier(0);
      __builtin_amdgcn_s_barrier();
    }
  }
#undef K4_STAGE

  // ---- fused epilogue: every lane holds one full T-row (b', c')
#pragma unroll
  for (int i = 0; i < 4; ++i) {
    float* ob = out + (size_t)bp[i] * (V_SZ * 3);
#pragma unroll
    for (int j = 0; j < 4; ++j) {
      const int v = n0 + noff + j*16 + lrow;
      if (v < V_SZ) {
        float p0 = b2f(pv[i][j][0]);
        float p1 = b2f(pv[i][j][1]);
        float p2 = b2f(pv[i][j][2]);
        f32x4 a = acc[i][j];
        ob[(size_t)v*3 + cp[i]] = a[0]*p0 + a[1]*p1 + a[2]*p2 + a[3] + tr[i];
      }
    }
  }
}

// ---------------------------------------------------------------------------
extern "C" void kernel_launch(void* const* d_in, const int* in_sizes, int n_in,
                              void* d_out, int out_size, void* d_ws, size_t ws_size,
                              hipStream_t stream) {
  const float* body_pose     = (const float*)d_in[0];
  const float* betas         = (const float*)d_in[1];
  const float* global_orient = (const float*)d_in[2];
  const float* transl        = (const float*)d_in[3];
  const float* v_template    = (const float*)d_in[4];
  const float* shapedirs     = (const float*)d_in[5];
  const float* posedirs      = (const float*)d_in[6];
  const float* J_template    = (const float*)d_in[7];
  const float* J_shapedirs   = (const float*)d_in[8];
  const float* lbsw          = (const float*)d_in[9];
  float* out = (float*)d_out;

  // workspace layout (67.6 MB total, all 16B-aligned):
  //   [0,        983040)   PF   1024*480*2
  //   [1048576,  4980736)  AH   12288*160*2 = 3.93 MB  (prep->k4)
  //   [6291456,  8503296)  WB   6912*160*2  = 2.21 MB  (prep->k4)
  //   [8503296, 28409856)  PDt  20736*480*2 = 19.9 MB  (prep->k2, planar rows)
  //   [28409856,70877184)  VP   1024*20736*2= 42.5 MB  (k2->k4, planar [b][c][v])
  char* ws = (char*)d_ws;
  u16* PF  = (u16*)(ws);
  u16* AH  = (u16*)(ws + 1048576u);
  u16* WB  = (u16*)(ws + 6291456u);
  u16* PDt = (u16*)(ws + 8503296u);
  u16* VP  = (u16*)(ws + 28409856u);

  k_prep<<<dim3(NK1 + NK0W + NK0), dim3(256), 0, stream>>>(
      posedirs, shapedirs, lbsw, body_pose, betas, global_orient,
      J_template, J_shapedirs, PDt, WB, AH, PF);
  k2_gemm<<<dim3(1344), dim3(256), 0, stream>>>(PF, PDt, v_template, VP);
  k4_blend<<<dim3(VPADB / 128, MROWS / 128), dim3(256), 0, stream>>>(AH, WB, VP, transl, out);
}

// Round 12
// 231.968 us; speedup vs baseline: 1.0859x; 1.0602x over previous
//
#include <hip/hip_runtime.h>

typedef unsigned short u16;
typedef __bf16  bf16x8 __attribute__((ext_vector_type(8)));
typedef float   f32x4  __attribute__((ext_vector_type(4)));
typedef unsigned int u32x4 __attribute__((ext_vector_type(4)));

#define B_SZ   1024
#define V_SZ   6890
#define VPADB  6912    /* 54*128 vertex pad for blend GEMM */
#define J_SZ   52
#define NB_SZ  16
#define NPOSE  459
#define N3     20670   /* V*3 */
#define NPAD   20736   /* 162*128 = 3*VPADB: padded N for k2 GEMM (planar c-planes) */
#define KG     480     /* 459 pose + 16 betas, zero-padded to 480 */
#define KA     160     /* blend K: 52 (Ahi*Whi) + 52 (Alo*Whi) + 52 (Ahi*Wlo) + 4 pad */
#define MROWS  12288   /* B_SZ * 12: M rows of blend GEMM (b*12 + c*4 + d) */

/* k_prep sub-grid: k1 blocks first (4 batches each), then k0w, then k0 tiles */
#define NK1    (B_SZ / 4)        /* 256  */
#define NK0W   (VPADB / 64)      /* 108  */
#define NK0    (648 * 8)         /* 5184: 32n x 64k tiles */

/* k1 per-group smem layout (4992 B): jts @0 (624) | G @624 (2496) | R @3120 (1872)
   AHs (3840) aliases @624 over G+R after both are dead (G copied to regs, R unused) */
#define K1G    4992

__constant__ int PARENTS_D[52] = {-1,0,0,0,1,2,3,4,5,6,7,8,9,9,9,12,13,14,16,17,18,19,20,22,23,
                                  20,25,26,20,28,29,20,31,32,20,34,35,21,37,38,21,40,41,21,43,44,
                                  21,46,47,21,49,50};

__device__ __forceinline__ u16 f2b(float f) {
  union { float f; unsigned u; } v; v.f = f;
  unsigned r = (v.u + 0x7FFFu + ((v.u >> 16) & 1u)) >> 16;
  return (u16)r;
}
__device__ __forceinline__ float b2f(u16 h) {
  union { unsigned u; float f; } v; v.u = ((unsigned)h) << 16;
  return v.f;
}
__device__ __forceinline__ void async16(const void* g, void* l) {
  __builtin_amdgcn_global_load_lds((const __attribute__((address_space(1))) void*)g,
                                   (__attribute__((address_space(3))) void*)l, 16, 0, 0);
}

// ---------------------------------------------------------------------------
// K_PREP: merged k1 + k0w + k0. NEW: smem cut 35328 -> 20480 B (8 blocks/CU,
// was 4). k1 re-sequenced so AHs aliases the dead G+R region: (1) R,jts;
// (2) PF write + chain; (3) G -> o regs + t_corr; barrier; (4) AHs slice
// writes + pad zeros (over old G/R space); barrier; (5) DMA out.
// ---------------------------------------------------------------------------
__global__ __launch_bounds__(256) void k_prep(const float* __restrict__ posedirs,
                                              const float* __restrict__ shapedirs,
                                              const float* __restrict__ lbsw,
                                              const float* __restrict__ body_pose,
                                              const float* __restrict__ betas,
                                              const float* __restrict__ global_orient,
                                              const float* __restrict__ J_template,
                                              const float* __restrict__ J_shapedirs,
                                              u16* __restrict__ PDt,
                                              u16* __restrict__ WB,
                                              u16* __restrict__ AH,
                                              u16* __restrict__ PF)
{
  __shared__ __align__(16) char smem[20480];   /* max(k0w 20480, k1 4*4992, k0 4608) */
  const int bid = blockIdx.x;
  const int tid = threadIdx.x;

  if (bid < NK1) {
    // ================= k1 body: 4 batches per block =======================
    const int g = tid >> 6;          // group 0..3
    const int t = tid & 63;          // lane within group
    const int b = bid * 4 + g;
    char* base = smem + g * K1G;
    float (*jts)[3] = (float(*)[3])(base);            //  624 B @0
    float (*G)[12]  = (float(*)[12])(base + 624);     // 2496 B @624
    float (*R)[9]   = (float(*)[9])(base + 3120);     // 1872 B @3120
    u16*   AHs      = (u16*)(base + 624);             // 3840 B, aliases G+R later

    // ---- phase 1: rot6d -> R, joints
    if (t < J_SZ) {
      const float* d6 = (t == 0) ? &global_orient[(size_t)b * 6]
                                 : &body_pose[((size_t)b * 51 + (t - 1)) * 6];
      float a1x = d6[0], a1y = d6[1], a1z = d6[2];
      float a2x = d6[3], a2y = d6[4], a2z = d6[5];
      float inv1 = rsqrtf(a1x*a1x + a1y*a1y + a1z*a1z);
      float b1x = a1x*inv1, b1y = a1y*inv1, b1z = a1z*inv1;
      float d   = b1x*a2x + b1y*a2y + b1z*a2z;
      float ux = a2x - d*b1x, uy = a2y - d*b1y, uz = a2z - d*b1z;
      float inv2 = rsqrtf(ux*ux + uy*uy + uz*uz);
      float b2x = ux*inv2, b2y = uy*inv2, b2z = uz*inv2;
      float b3x = b1y*b2z - b1z*b2y;
      float b3y = b1z*b2x - b1x*b2z;
      float b3z = b1x*b2y - b1y*b2x;
      R[t][0]=b1x; R[t][1]=b1y; R[t][2]=b1z;
      R[t][3]=b2x; R[t][4]=b2y; R[t][5]=b2z;
      R[t][6]=b3x; R[t][7]=b3y; R[t][8]=b3z;
#pragma unroll
      for (int c = 0; c < 3; ++c) {
        float s = J_template[t*3 + c];
#pragma unroll
        for (int k = 0; k < NB_SZ; ++k)
          s += betas[(size_t)b*NB_SZ + k] * J_shapedirs[(t*3 + c)*NB_SZ + k];
        jts[t][c] = s;
      }
    }
    __syncthreads();

    // ---- phase 2: PF write (all lanes, reads R) + chain (t<3, writes G)
    for (int k = t; k < KG; k += 64) {  // PF row: pose_feature | betas | 0-pad
      float val = 0.f;
      if (k < NPOSE) {
        int j  = k / 9 + 1;
        int rc = k - (j - 1) * 9;
        val = R[j][rc] - ((rc == 0 || rc == 4 || rc == 8) ? 1.f : 0.f);
      } else if (k < NPOSE + NB_SZ) {
        val = betas[(size_t)b*NB_SZ + (k - NPOSE)];
      }
      PF[(size_t)b*KG + k] = f2b(val);
    }
    if (t < 3) {   // kinematic chain: c-rows independent -> 3-lane parallel
      const int c = t;
      G[0][c*4+0] = R[0][c*3+0];
      G[0][c*4+1] = R[0][c*3+1];
      G[0][c*4+2] = R[0][c*3+2];
      G[0][c*4+3] = jts[0][c];
      for (int j = 1; j < J_SZ; ++j) {
        int p = PARENTS_D[j];
        float r0 = jts[j][0] - jts[p][0];
        float r1 = jts[j][1] - jts[p][1];
        float r2 = jts[j][2] - jts[p][2];
        float g0 = G[p][c*4+0], g1 = G[p][c*4+1], g2 = G[p][c*4+2];
        G[j][c*4+0] = g0*R[j][0] + g1*R[j][3] + g2*R[j][6];
        G[j][c*4+1] = g0*R[j][1] + g1*R[j][4] + g2*R[j][7];
        G[j][c*4+2] = g0*R[j][2] + g1*R[j][5] + g2*R[j][8];
        G[j][c*4+3] = g0*r0 + g1*r1 + g2*r2 + G[p][c*4+3];
      }
    }
    __syncthreads();

    // ---- phase 3: G -> o regs + t_corr (jts still live; R, G dead after)
    float o[12];
    if (t < J_SZ) {
#pragma unroll
      for (int i = 0; i < 12; ++i) o[i] = G[t][i];
#pragma unroll
      for (int c = 0; c < 3; ++c)
        o[c*4+3] -= o[c*4+0]*jts[t][0] + o[c*4+1]*jts[t][1] + o[c*4+2]*jts[t][2];
    }
    __syncthreads();   // all G reads done -> AHs may overwrite G/R

    // ---- phase 4: AHs hi/lo slices (k-slot = joint index) + pad zeros
    if (t < J_SZ) {
#pragma unroll
      for (int cd = 0; cd < 12; ++cd) {
        u16 hi = f2b(o[cd]);
        u16 lo = f2b(o[cd] - b2f(hi));
        AHs[cd*KA + t]        = hi;   // * Whi
        AHs[cd*KA + 52 + t]   = lo;   // * Whi
        AHs[cd*KA + 104 + t]  = hi;   // * Wlo
      }
    }
    if (t < 48) AHs[(t >> 2)*KA + 156 + (t & 3)] = 0;   // k 156..159 pad
    __syncthreads();

    // ---- phase 5: DMA AHs -> global
    unsigned* dst = (unsigned*)(AH + (size_t)b * 12 * KA);
    for (int i = t; i < 12 * KA / 2; i += 64) dst[i] = ((const unsigned*)AHs)[i];

  } else if (bid < NK1 + NK0W) {
    // ================= k0w body: WB[v][160] ===============================
    u16* wtile = (u16*)smem;                  // 64 * KA u16 = 20480 B
    const int v0  = (bid - NK1) * 64;
    const int vl  = tid >> 2;
    const int v   = v0 + vl;
    const int jseg = (tid & 3) * 13;

    wtile[vl * KA + 156 + (tid & 3)] = 0;     // zero k 156..159 pad

#pragma unroll
    for (int jj = 0; jj < 13; ++jj) {
      int j = jseg + jj;
      float wv = (v < V_SZ) ? lbsw[(size_t)v * J_SZ + j] : 0.f;
      u16 hi = f2b(wv);
      u16 lo = f2b(wv - b2f(hi));
      wtile[vl * KA + j]        = hi;   // pairs with A_hi
      wtile[vl * KA + 52 + j]   = hi;   // pairs with A_lo
      wtile[vl * KA + 104 + j]  = lo;   // pairs with A_hi
    }
    __syncthreads();
    u32x4*       dst = (u32x4*)(WB + (size_t)v0 * KA);
    const u32x4* src = (const u32x4*)wtile;
    for (int i = tid; i < 64 * KA / 8; i += 256) dst[i] = src[i];

  } else {
    // ================= k0 body: PDt[n'][k], planar n', 32n x 64k tile =====
    u16* tile = (u16*)smem;                   // [32][72] u16, 4608 B
    const int cb = bid - NK1 - NK0W;
    const int nt = cb % 648;
    const int kt = cb / 648;                  // 0..7
    const int n0 = nt * 32;
    const int k0 = kt * 64;
    const int tx = tid & 31;                  // n lane
    const int ty = tid >> 5;                  // 0..7
    const int n  = n0 + tx;
#pragma unroll
    for (int i = 0; i < 8; ++i) {
      int k = k0 + ty + i*8;                  // k0..k0+63
      float val = 0.f;
      if (n < N3) {
        if (k < NPOSE)              val = posedirs[(size_t)k * N3 + n];
        else if (k < NPOSE + NB_SZ) val = shapedirs[(size_t)n * NB_SZ + (k - NPOSE)];
      }
      tile[tx*72 + ty + i*8] = f2b(val);
    }
    __syncthreads();
    // store: 8 threads cover one n-row's 64 k's = 128 B contiguous (full line)
    const int nl = tid >> 3;                  // 0..31
    const int ks = (tid & 7) * 8;             // 0,8,..,56
    const int kb = k0 + ks;
    if (kb < KG) {
      int n2 = n0 + nl;                       // < 20736 by grid
      int vv = n2 / 3;
      int cc = n2 - vv * 3;                   // planar permute (bijective)
      *(u32x4*)&PDt[((size_t)cc * VPADB + vv) * KG + kb] =
          *(const u32x4*)&tile[nl*72 + ks];
    }
  }
}

// ---------------------------------------------------------------------------
// K2: v_posed = PF(B,KG) @ PDt^T + bias. (r9-verified, unchanged: XCD-grouped
// 1D grid 1344, 2-buffer counted-vmcnt K-loop, planar VP output.)
// ---------------------------------------------------------------------------
__global__ __launch_bounds__(256) void k2_gemm(const u16* __restrict__ PF,
                                               const u16* __restrict__ PDt,
                                               const float* __restrict__ vtmpl,
                                               u16* __restrict__ VP)
{
  __shared__ __align__(16) u16 lA[2][4096];
  __shared__ __align__(16) u16 lB[2][4096];
  const int bid = blockIdx.x;
  const int nt  = (bid & 7) + ((bid >> 6) << 3);   // n-tile 0..167 (use <162)
  const int bt  = (bid >> 3) & 7;                  // b-tile 0..7
  if (nt >= 162) return;
  const int tid  = threadIdx.x;
  const int lane = tid & 63;
  const int w    = tid >> 6;
  const int n0   = nt * 128;
  const int b0   = bt * 128;
  const int moff = (w & 1) * 64;
  const int noff = (w >> 1) * 64;
  const int q    = lane >> 4;
  const int lrow = lane & 15;

  f32x4 acc[4][4];
#pragma unroll
  for (int i = 0; i < 4; ++i)
#pragma unroll
    for (int j = 0; j < 4; ++j) { f32x4 z = {0.f,0.f,0.f,0.f}; acc[i][j] = z; }

  int aoff[4], boff[4];
#pragma unroll
  for (int i = 0; i < 4; ++i) {
    int ra = moff + i*16 + lrow;
    aoff[i] = ra*32 + (q ^ ((ra + (ra >> 2)) & 3)) * 8;
    int rb = noff + i*16 + lrow;
    boff[i] = rb*32 + (q ^ ((rb + (rb >> 2)) & 3)) * 8;
  }
  int srow[2], schunk[2];
#pragma unroll
  for (int t = 0; t < 2; ++t) {
    int i = (t*4 + w)*64 + lane;     // slot in [0,512)
    int r = i >> 2;
    srow[t]   = r;
    schunk[t] = (i & 3) ^ ((r + (r >> 2)) & 3);
  }

#define K2_STAGE(buf, seg)                                                          \
  {                                                                                 \
    const int kk = (seg) * 32;                                                      \
    _Pragma("unroll")                                                               \
    for (int t = 0; t < 2; ++t) {                                                   \
      async16(PF  + (size_t)(b0 + srow[t])*KG + kk + schunk[t]*8,                   \
              &lA[buf][(t*4 + w)*512]);                                             \
      async16(PDt + (size_t)(n0 + srow[t])*KG + kk + schunk[t]*8,                   \
              &lB[buf][(t*4 + w)*512]);                                             \
    }                                                                               \
  }

  K2_STAGE(0, 0);

  for (int seg = 0; seg < 15; ++seg) {
    const int cur = seg & 1;
    if (seg < 14) K2_STAGE(cur ^ 1, seg + 1);
    __builtin_amdgcn_sched_barrier(0);
    if (seg < 14) asm volatile("s_waitcnt vmcnt(4)" ::: "memory");
    else          asm volatile("s_waitcnt vmcnt(0)" ::: "memory");
    __builtin_amdgcn_s_barrier();
    __builtin_amdgcn_sched_barrier(0);
    bf16x8 af[4], bfv[4];
#pragma unroll
    for (int i = 0; i < 4; ++i) af[i]  = *(const bf16x8*)&lA[cur][aoff[i]];
#pragma unroll
    for (int i = 0; i < 4; ++i) bfv[i] = *(const bf16x8*)&lB[cur][boff[i]];
#pragma unroll
    for (int i = 0; i < 4; ++i)
#pragma unroll
      for (int j = 0; j < 4; ++j)
        acc[i][j] = __builtin_amdgcn_mfma_f32_16x16x32_bf16(af[i], bfv[j], acc[i][j], 0, 0, 0);
    if (seg < 14) {                     // protect buf reuse by next stage
      __builtin_amdgcn_sched_barrier(0);
      __builtin_amdgcn_s_barrier();
    }
  }
#undef K2_STAGE

#pragma unroll
  for (int i = 0; i < 4; ++i) {
    int brow = b0 + moff + i*16 + q*4;
#pragma unroll
    for (int j = 0; j < 4; ++j) {
      int np = n0 + noff + j*16 + lrow;        // planar column: c*VPADB + v
      int vv = np % VPADB;
      int cc = np / VPADB;
      float bias = (vv < V_SZ) ? vtmpl[vv*3 + cc] : 0.f;
#pragma unroll
      for (int r = 0; r < 4; ++r)
        VP[(size_t)(brow + r)*NPAD + np] = f2b(acc[i][j][r] + bias);
    }
  }
}

// ---------------------------------------------------------------------------
// K4: MFMA blend, M = B*12. r9-verified core (2-buffer counted-vmcnt, planar
// VP prefetch first, fused epilogue). NEW: XCD-chunked 1D grid — XCD k owns
// W in [648k, 648(k+1)) = m-tiles [12k,12k+12) x all n -> AH slice (480 KB)
// + WB (2.2 MB) L2-resident per XCD (r7-measured FETCH 45 -> 37.5 MB).
// ---------------------------------------------------------------------------
__global__ __launch_bounds__(256) void k4_blend(const u16* __restrict__ AH,
                                                const u16* __restrict__ WB,
                                                const u16* __restrict__ VP,
                                                const float* __restrict__ transl,
                                                float* __restrict__ out)
{
  __shared__ __align__(16) u16 lA[2][4096];   // 2 x 8 KB, swizzled [row][32k]
  __shared__ __align__(16) u16 lB[2][4096];   // 2 x 8 KB
  const int tid  = threadIdx.x;
  const int lane = tid & 63;
  const int w    = tid >> 6;
  const int W    = (blockIdx.x & 7) * 648 + (blockIdx.x >> 3);
  const int n0   = (W % 54) * 128;            // vertex tile
  const int m0   = (W / 54) * 128;            // (b,cd12) row tile
  const int moff = (w & 1) * 64;
  const int noff = (w >> 1) * 64;
  const int q    = lane >> 4;
  const int lrow = lane & 15;

  int srow[2], schunk[2];
#pragma unroll
  for (int t = 0; t < 2; ++t) {
    int i = (t*4 + w)*64 + lane;
    int r = i >> 2;
    srow[t]   = r;
    schunk[t] = (i & 3) ^ ((r + (r >> 2)) & 3);
  }

#define K4_STAGE(buf, seg)                                                          \
  {                                                                                 \
    const int kk = (seg) * 32;                                                      \
    _Pragma("unroll")                                                               \
    for (int t = 0; t < 2; ++t) {                                                   \
      async16(AH + (size_t)(m0 + srow[t])*KA + kk + schunk[t]*8,                    \
              &lA[buf][(t*4 + w)*512]);                                             \
      async16(WB + (size_t)(n0 + srow[t])*KA + kk + schunk[t]*8,                    \
              &lB[buf][(t*4 + w)*512]);                                             \
    }                                                                               \
  }

  // ---- epilogue operand prefetch FIRST (oldest vmem -> drains under stage).
  int   bp[4], cp[4];
#pragma unroll
  for (int i = 0; i < 4; ++i) {
    int gq = (m0 + moff + i*16) / 4 + q;   // quarter-row index
    bp[i] = gq / 3;                        // batch
    cp[i] = gq - bp[i]*3;                  // coordinate row
  }
  u16 pv[4][4][3];
#pragma unroll
  for (int i = 0; i < 4; ++i) {
    const u16* vpb = VP + (size_t)bp[i] * NPAD;
#pragma unroll
    for (int j = 0; j < 4; ++j) {
      const int v = n0 + noff + j*16 + lrow;   // < VPADB; planes contiguous in v
      pv[i][j][0] = vpb[0*VPADB + v];
      pv[i][j][1] = vpb[1*VPADB + v];
      pv[i][j][2] = vpb[2*VPADB + v];
    }
  }
  float tr[4];
#pragma unroll
  for (int i = 0; i < 4; ++i) tr[i] = transl[bp[i]*3 + cp[i]];

  // ---- prologue stage seg0
  K4_STAGE(0, 0);

  f32x4 acc[4][4];
#pragma unroll
  for (int i = 0; i < 4; ++i)
#pragma unroll
    for (int j = 0; j < 4; ++j) { f32x4 z = {0.f,0.f,0.f,0.f}; acc[i][j] = z; }

  int aoff[4], boff[4];
#pragma unroll
  for (int i = 0; i < 4; ++i) {
    int ra = moff + i*16 + lrow;
    aoff[i] = ra*32 + (q ^ ((ra + (ra >> 2)) & 3)) * 8;
    int rb = noff + i*16 + lrow;
    boff[i] = rb*32 + (q ^ ((rb + (rb >> 2)) & 3)) * 8;
  }

  // ---- T4 2-phase K-loop: stage(seg+1) stays in flight across the barrier
#pragma unroll
  for (int seg = 0; seg < 5; ++seg) {
    const int cur = seg & 1;
    if (seg < 4) K4_STAGE(cur ^ 1, seg + 1);
    __builtin_amdgcn_sched_barrier(0);
    if (seg < 4) asm volatile("s_waitcnt vmcnt(4)" ::: "memory");
    else         asm volatile("s_waitcnt vmcnt(0)" ::: "memory");
    __builtin_amdgcn_s_barrier();
    __builtin_amdgcn_sched_barrier(0);
    bf16x8 af[4], bfv[4];
#pragma unroll
    for (int i = 0; i < 4; ++i) af[i]  = *(const bf16x8*)&lA[cur][aoff[i]];
#pragma unroll
    for (int i = 0; i < 4; ++i) bfv[i] = *(const bf16x8*)&lB[cur][boff[i]];
#pragma unroll
    for (int i = 0; i < 4; ++i)
#pragma unroll
      for (int j = 0; j < 4; ++j)
        acc[i][j] = __builtin_amdgcn_mfma_f32_16x16x32_bf16(af[i], bfv[j], acc[i][j], 0, 0, 0);
    if (seg < 4) {                      // protect buf reuse by next stage
      __builtin_amdgcn_sched_barrier(0);
      __builtin_amdgcn_s_barrier();
    }
  }
#undef K4_STAGE

  // ---- fused epilogue: every lane holds one full T-row (b', c')
#pragma unroll
  for (int i = 0; i < 4; ++i) {
    float* ob = out + (size_t)bp[i] * (V_SZ * 3);
#pragma unroll
    for (int j = 0; j < 4; ++j) {
      const int v = n0 + noff + j*16 + lrow;
      if (v < V_SZ) {
        float p0 = b2f(pv[i][j][0]);
        float p1 = b2f(pv[i][j][1]);
        float p2 = b2f(pv[i][j][2]);
        f32x4 a = acc[i][j];
        ob[(size_t)v*3 + cp[i]] = a[0]*p0 + a[1]*p1 + a[2]*p2 + a[3] + tr[i];
      }
    }
  }
}

// ---------------------------------------------------------------------------
extern "C" void kernel_launch(void* const* d_in, const int* in_sizes, int n_in,
                              void* d_out, int out_size, void* d_ws, size_t ws_size,
                              hipStream_t stream) {
  const float* body_pose     = (const float*)d_in[0];
  const float* betas         = (const float*)d_in[1];
  const float* global_orient = (const float*)d_in[2];
  const float* transl        = (const float*)d_in[3];
  const float* v_template    = (const float*)d_in[4];
  const float* shapedirs     = (const float*)d_in[5];
  const float* posedirs      = (const float*)d_in[6];
  const float* J_template    = (const float*)d_in[7];
  const float* J_shapedirs   = (const float*)d_in[8];
  const float* lbsw          = (const float*)d_in[9];
  float* out = (float*)d_out;

  // workspace layout (67.6 MB total, all 16B-aligned):
  //   [0,        983040)   PF   1024*480*2
  //   [1048576,  4980736)  AH   12288*160*2 = 3.93 MB  (prep->k4)
  //   [6291456,  8503296)  WB   6912*160*2  = 2.21 MB  (prep->k4)
  //   [8503296, 28409856)  PDt  20736*480*2 = 19.9 MB  (prep->k2, planar rows)
  //   [28409856,70877184)  VP   1024*20736*2= 42.5 MB  (k2->k4, planar [b][c][v])
  char* ws = (char*)d_ws;
  u16* PF  = (u16*)(ws);
  u16* AH  = (u16*)(ws + 1048576u);
  u16* WB  = (u16*)(ws + 6291456u);
  u16* PDt = (u16*)(ws + 8503296u);
  u16* VP  = (u16*)(ws + 28409856u);

  k_prep<<<dim3(NK1 + NK0W + NK0), dim3(256), 0, stream>>>(
      posedirs, shapedirs, lbsw, body_pose, betas, global_orient,
      J_template, J_shapedirs, PDt, WB, AH, PF);
  k2_gemm<<<dim3(1344), dim3(256), 0, stream>>>(PF, PDt, v_template, VP);
  k4_blend<<<dim3(54 * 96), dim3(256), 0, stream>>>(AH, WB, VP, transl, out);
}